// Round 7
// baseline (611.114 us; speedup 1.0000x reference)
//
#include <hip/hip_runtime.h>
#include <hip/hip_bf16.h>
#include <math.h>

// Problem constants
#define NPTS 8192
#define BDIM 4
#define BN   32768   // BDIM*NPTS
#define CDIM 256
#define KNN  16
#define NNCOL 32

typedef __attribute__((ext_vector_type(8))) short short8_t;
typedef __attribute__((ext_vector_type(4))) float f32x4;

// ---------------------------------------------------------------------------
// bf16 helpers
// ---------------------------------------------------------------------------
__device__ __forceinline__ ushort bf16_rne(float f) {
  unsigned int u = __float_as_uint(f);
  u += 0x7fffu + ((u >> 16) & 1u);
  return (ushort)(u >> 16);
}
__device__ __forceinline__ void bf16_split(float f, ushort& h, ushort& l) {
  unsigned int u = __float_as_uint(f);
  h = (ushort)(u >> 16);
  float fh = __uint_as_float(u & 0xffff0000u);
  l = (ushort)(__float_as_uint(f - fh) >> 16);
}
__device__ __forceinline__ float bf16_tof(ushort h) {
  return __uint_as_float(((unsigned int)h) << 16);
}
__device__ __forceinline__ float gelu_exact(float z) {
  return 0.5f * z * (1.0f + erff(z * 0.70710678118654752f));
}

// ---------------------------------------------------------------------------
// Weight prep: transpose fp32 [R][Cc] -> hi/lo bf16 [Cc][R] (k-major for GEMM B)
// ---------------------------------------------------------------------------
__global__ __launch_bounds__(256) void wsplit_kernel(
    const float* __restrict__ in, ushort* __restrict__ oh,
    ushort* __restrict__ ol, int R, int Cc) {
  __shared__ float tile[32][33];
  const int tx = threadIdx.x & 31, ty = threadIdx.x >> 5;
  const int r0 = blockIdx.y * 32, c0 = blockIdx.x * 32;
  #pragma unroll
  for (int i = 0; i < 4; i++)
    tile[ty + 8 * i][tx] = in[(size_t)(r0 + ty + 8 * i) * Cc + c0 + tx];
  __syncthreads();
  #pragma unroll
  for (int i = 0; i < 4; i++) {
    const int cc = ty + 8 * i;
    ushort h, l;
    bf16_split(tile[tx][cc], h, l);
    oh[(size_t)(c0 + cc) * R + r0 + tx] = h;
    ol[(size_t)(c0 + cc) * R + r0 + tx] = l;
  }
}

// ---------------------------------------------------------------------------
// Fused LN stats + apply: x fp32 [rows][256] -> pre-split hi/lo bf16 of LN(x).
// ---------------------------------------------------------------------------
__global__ __launch_bounds__(256) void ln_apply_kernel(
    const float* __restrict__ x, const float* __restrict__ g,
    const float* __restrict__ b, ushort* __restrict__ oh,
    ushort* __restrict__ ol) {
  const int row = blockIdx.x * 4 + (threadIdx.x >> 6);
  const int l = threadIdx.x & 63;
  const float4 v = *(const float4*)(x + (size_t)row * CDIM + l * 4);
  float s  = v.x + v.y + v.z + v.w;
  float sq = v.x * v.x + v.y * v.y + v.z * v.z + v.w * v.w;
  #pragma unroll
  for (int off = 1; off < 64; off <<= 1) {
    s  += __shfl_xor(s, off);
    sq += __shfl_xor(sq, off);
  }
  const float m = s * (1.0f / 256.0f);
  const float r = rsqrtf(sq * (1.0f / 256.0f) - m * m + 1e-5f);
  const float4 gv = *(const float4*)(g + l * 4);
  const float4 bv = *(const float4*)(b + l * 4);
  const float y0 = (v.x - m) * r * gv.x + bv.x;
  const float y1 = (v.y - m) * r * gv.y + bv.y;
  const float y2 = (v.z - m) * r * gv.z + bv.z;
  const float y3 = (v.w - m) * r * gv.w + bv.w;
  ushort4 hv, lv;
  bf16_split(y0, hv.x, lv.x); bf16_split(y1, hv.y, lv.y);
  bf16_split(y2, hv.z, lv.z); bf16_split(y3, hv.w, lv.w);
  *(ushort4*)(oh + (size_t)row * CDIM + l * 4) = hv;
  *(ushort4*)(ol + (size_t)row * CDIM + l * 4) = lv;
}

// ---------------------------------------------------------------------------
// MFMA bf16x3 GEMM, pre-split operands (verified round 3/6 structure).
// ---------------------------------------------------------------------------
template <int EPI>
__global__ __launch_bounds__(256) void gemm_bf3(
    const ushort* __restrict__ AH, const ushort* __restrict__ AL,
    const ushort* __restrict__ BH, const ushort* __restrict__ BL,
    const float* __restrict__ bias, float* __restrict__ Cf,
    ushort* __restrict__ CH, ushort* __restrict__ CL,
    const float* __restrict__ res, int M, int Nn, int Kk) {
  __shared__ __align__(16) ushort AsH[128 * 32];
  __shared__ __align__(16) ushort AsL[128 * 32];
  __shared__ __align__(16) ushort BsH[128 * 32];
  __shared__ __align__(16) ushort BsL[128 * 32];

  const int t = threadIdx.x;
  const int w = t >> 6;
  const int l = t & 63;
  const int la = l & 15;
  const int lb = l >> 4;
  const int wr = w >> 1;
  const int wc = w & 1;
  const int m0 = blockIdx.y * 128;
  const int n0 = blockIdx.x * 128;

  f32x4 acc[4][4];
  #pragma unroll
  for (int i = 0; i < 4; i++)
    #pragma unroll
    for (int j = 0; j < 4; j++) acc[i][j] = (f32x4){0.f, 0.f, 0.f, 0.f};

  for (int k0 = 0; k0 < Kk; k0 += 32) {
    #pragma unroll
    for (int gi = 0; gi < 2; gi++) {
      const int g = t + gi * 256;
      const int row = g >> 2;
      const int kg = (g & 3) * 8;
      const int lds_off = row * 32 + (kg ^ ((row & 3) << 3));
      const size_t ga = (size_t)(m0 + row) * Kk + k0 + kg;
      const size_t gb = (size_t)(n0 + row) * Kk + k0 + kg;
      *(short8_t*)&AsH[lds_off] = *(const short8_t*)(AH + ga);
      *(short8_t*)&AsL[lds_off] = *(const short8_t*)(AL + ga);
      *(short8_t*)&BsH[lds_off] = *(const short8_t*)(BH + gb);
      *(short8_t*)&BsL[lds_off] = *(const short8_t*)(BL + gb);
    }
    __syncthreads();

    short8_t aH[4], aL[4], bH[4], bL[4];
    #pragma unroll
    for (int i = 0; i < 4; i++) {
      const int row = wr * 64 + i * 16 + la;
      const int off = row * 32 + ((lb * 8) ^ ((row & 3) << 3));
      aH[i] = *(const short8_t*)&AsH[off];
      aL[i] = *(const short8_t*)&AsL[off];
    }
    #pragma unroll
    for (int j = 0; j < 4; j++) {
      const int row = wc * 64 + j * 16 + la;
      const int off = row * 32 + ((lb * 8) ^ ((row & 3) << 3));
      bH[j] = *(const short8_t*)&BsH[off];
      bL[j] = *(const short8_t*)&BsL[off];
    }
    #pragma unroll
    for (int i = 0; i < 4; i++)
      #pragma unroll
      for (int j = 0; j < 4; j++) {
        acc[i][j] = __builtin_amdgcn_mfma_f32_16x16x32_bf16(aH[i], bH[j], acc[i][j], 0, 0, 0);
        acc[i][j] = __builtin_amdgcn_mfma_f32_16x16x32_bf16(aH[i], bL[j], acc[i][j], 0, 0, 0);
        acc[i][j] = __builtin_amdgcn_mfma_f32_16x16x32_bf16(aL[i], bH[j], acc[i][j], 0, 0, 0);
      }
    __syncthreads();
  }

  const int colBase = n0 + wc * 64 + la;
  float biasv[4] = {0.f, 0.f, 0.f, 0.f};
  if (EPI >= 2) {
    #pragma unroll
    for (int j = 0; j < 4; j++) biasv[j] = bias[colBase + j * 16];
  }
  #pragma unroll
  for (int i = 0; i < 4; i++) {
    #pragma unroll
    for (int r = 0; r < 4; r++) {
      const int row = m0 + wr * 64 + i * 16 + lb * 4 + r;
      #pragma unroll
      for (int j = 0; j < 4; j++) {
        const int col = colBase + j * 16;
        float o = acc[i][j][r] + biasv[j];
        if (EPI == 0) {
          CH[(size_t)row * Nn + col] = bf16_rne(o);
        } else if (EPI == 2) {
          o += res[(size_t)row * Nn + col];
          Cf[(size_t)row * Nn + col] = o;
        } else {  // EPI == 3
          o = gelu_exact(o);
          ushort h, lo2;
          bf16_split(o, h, lo2);
          CH[(size_t)row * Nn + col] = h;
          CL[(size_t)row * Nn + col] = lo2;
        }
      }
    }
  }
}

// ---------------------------------------------------------------------------
// Fused attention v3:
//  Phase 1 (per wave, 2 points): shuffle-free scores (lane l = head l>>4,
//  neighbor l&15), softmax, then gather V + pe-basis u, accumulating
//  ov[c] and s[h][c'] (s stored bf16 in swizzled LDS).
//  Phase 2: pe = s @ w_d2 via MFMA (w_d2 pre-split k-major bf16), fused add
//  of ov(+b_d2), output pre-split hi/lo bf16.
// ---------------------------------------------------------------------------
__global__ __launch_bounds__(256) void attn_kernel(
    const ushort* __restrict__ qkv, const int* __restrict__ nns,
    const float* __restrict__ xyz, const float* __restrict__ w_d1,
    const float* __restrict__ b_d1, const ushort* __restrict__ W2H,
    const float* __restrict__ b_d2, ushort* __restrict__ outH,
    ushort* __restrict__ outL) {
  __shared__ __align__(16) ushort s_lds[32 * 256];  // rows (p*4+h), k-major, swizzled
  __shared__ __align__(16) float ov_lds[8][256];
  __shared__ float a_lds[8][64];

  const int t = threadIdx.x;
  const int w = t >> 6;
  const int l = t & 63;
  const int h = l >> 4;     // head (both for c0-quad and for this lane's score)
  const int j16 = l & 15;   // this lane's score neighbor
  const int c0 = l * 4;
  const int blk = blockIdx.x;

  const float4 w10 = *(const float4*)(w_d1 + c0);
  const float4 w11 = *(const float4*)(w_d1 + 256 + c0);
  const float4 b1v = *(const float4*)(b_d1 + c0);
  const float4 b2v = *(const float4*)(b_d2 + c0);

  for (int pl = 0; pl < 2; pl++) {
    const int p  = w * 2 + pl;
    const int gp = blk * 8 + p;
    const int b  = gp >> 13;

    const float2 xy0 = *(const float2*)(xyz + gp * 2);

    int rowj[KNN];
    #pragma unroll
    for (int j = 0; j < KNN; j++) rowj[j] = (b << 13) + nns[gp * NNCOL + j];

    // ---- scores: lane l computes full 64-ch dot for (head h, neighbor j16)
    const size_t qbase = (size_t)gp * 768 + (h << 6);
    const size_t kbase = (size_t)rowj[j16] * 768 + 256 + (h << 6);
    float d = 0.f;
    #pragma unroll
    for (int u = 0; u < 8; u++) {
      const short8_t qv = *(const short8_t*)(qkv + qbase + u * 8);
      const short8_t kv = *(const short8_t*)(qkv + kbase + u * 8);
      #pragma unroll
      for (int e = 0; e < 8; e++)
        d += bf16_tof((ushort)qv[e]) * bf16_tof((ushort)kv[e]);
    }
    const float myscore = d * 0.125f;  // 1/sqrt(64)

    // softmax across the 16-lane group (axis j)
    float mx = myscore;
    mx = fmaxf(mx, __shfl_xor(mx, 1)); mx = fmaxf(mx, __shfl_xor(mx, 2));
    mx = fmaxf(mx, __shfl_xor(mx, 4)); mx = fmaxf(mx, __shfl_xor(mx, 8));
    const float e = __expf(myscore - mx);
    float sum = e;
    sum += __shfl_xor(sum, 1); sum += __shfl_xor(sum, 2);
    sum += __shfl_xor(sum, 4); sum += __shfl_xor(sum, 8);
    a_lds[p][l] = e / sum;  // l = h*16 + j
    __syncthreads();

    // ---- V + pe-basis accumulation over the lane's channel quad c0
    float sacc[4][4] = {};
    float4 ov = {0.f, 0.f, 0.f, 0.f};
    #pragma unroll
    for (int j = 0; j < KNN; j++) {
      const int r = rowj[j];
      const ushort4 vu = *(const ushort4*)(qkv + (size_t)r * 768 + 512 + c0);
      const float v0 = bf16_tof(vu.x), v1 = bf16_tof(vu.y);
      const float v2 = bf16_tof(vu.z), v3 = bf16_tof(vu.w);
      const float2 xyj = *(const float2*)(xyz + r * 2);
      const float rx = xy0.x - xyj.x;
      const float ry = xy0.y - xyj.y;
      const float u0 = fmaxf(rx * w10.x + ry * w11.x + b1v.x, 0.f);
      const float u1 = fmaxf(rx * w10.y + ry * w11.y + b1v.y, 0.f);
      const float u2 = fmaxf(rx * w10.z + ry * w11.z + b1v.z, 0.f);
      const float u3 = fmaxf(rx * w10.w + ry * w11.w + b1v.w, 0.f);
      const float a0 = a_lds[p][0 * 16 + j];
      const float a1 = a_lds[p][1 * 16 + j];
      const float a2 = a_lds[p][2 * 16 + j];
      const float a3 = a_lds[p][3 * 16 + j];
      sacc[0][0] += a0 * u0; sacc[0][1] += a0 * u1; sacc[0][2] += a0 * u2; sacc[0][3] += a0 * u3;
      sacc[1][0] += a1 * u0; sacc[1][1] += a1 * u1; sacc[1][2] += a1 * u2; sacc[1][3] += a1 * u3;
      sacc[2][0] += a2 * u0; sacc[2][1] += a2 * u1; sacc[2][2] += a2 * u2; sacc[2][3] += a2 * u3;
      sacc[3][0] += a3 * u0; sacc[3][1] += a3 * u1; sacc[3][2] += a3 * u2; sacc[3][3] += a3 * u3;
      const float aown = a_lds[p][(h << 4) + j];
      ov.x += aown * v0; ov.y += aown * v1;
      ov.z += aown * v2; ov.w += aown * v3;
    }
    // s -> bf16 swizzled LDS (row = p*4+h, k = c')
    #pragma unroll
    for (int hh = 0; hh < 4; hh++) {
      const int row = p * 4 + hh;
      ushort4 sv;
      sv.x = bf16_rne(sacc[hh][0]); sv.y = bf16_rne(sacc[hh][1]);
      sv.z = bf16_rne(sacc[hh][2]); sv.w = bf16_rne(sacc[hh][3]);
      *(ushort4*)&s_lds[row * 256 + (c0 ^ ((row & 15) << 3))] = sv;
    }
    float4 ovw;
    ovw.x = ov.x + b2v.x; ovw.y = ov.y + b2v.y;
    ovw.z = ov.z + b2v.z; ovw.w = ov.w + b2v.w;
    *(float4*)&ov_lds[p][c0] = ovw;
  }
  __syncthreads();

  // ---- Phase 2: pe = s @ w_d2 via MFMA. Wave w covers cols w*64..w*64+63
  // (= head w). A = s_lds [32 rows][256 k]; B = W2H [n][k] from global.
  const int la = l & 15;
  const int lb = l >> 4;
  f32x4 acc2[2][4];
  #pragma unroll
  for (int mf = 0; mf < 2; mf++)
    #pragma unroll
    for (int nf = 0; nf < 4; nf++) acc2[mf][nf] = (f32x4){0.f, 0.f, 0.f, 0.f};

  #pragma unroll
  for (int ks = 0; ks < 8; ks++) {
    const int k8 = lb * 8 + ks * 32;
    short8_t av[2], bv[4];
    #pragma unroll
    for (int mf = 0; mf < 2; mf++) {
      const int row = mf * 16 + la;
      av[mf] = *(const short8_t*)&s_lds[row * 256 + (k8 ^ ((row & 15) << 3))];
    }
    #pragma unroll
    for (int nf = 0; nf < 4; nf++) {
      const int n = (w << 6) + nf * 16 + la;
      bv[nf] = *(const short8_t*)(W2H + (size_t)n * 256 + k8);
    }
    #pragma unroll
    for (int mf = 0; mf < 2; mf++)
      #pragma unroll
      for (int nf = 0; nf < 4; nf++)
        acc2[mf][nf] = __builtin_amdgcn_mfma_f32_16x16x32_bf16(
            av[mf], bv[nf], acc2[mf][nf], 0, 0, 0);
  }

  // Epilogue: useful lane data = acc2[mf][nf][r=w]; point p = mf*4+lb,
  // col c = w*64 + nf*16 + la. Add ov(+b_d2), split, store.
  #pragma unroll
  for (int mf = 0; mf < 2; mf++) {
    const int p = mf * 4 + lb;
    const size_t gp = (size_t)(blk * 8 + p);
    #pragma unroll
    for (int nf = 0; nf < 4; nf++) {
      const int c = (w << 6) + nf * 16 + la;
      float pe;
      if (w == 0)      pe = acc2[mf][nf][0];
      else if (w == 1) pe = acc2[mf][nf][1];
      else if (w == 2) pe = acc2[mf][nf][2];
      else             pe = acc2[mf][nf][3];
      const float o = pe + ov_lds[p][c];
      ushort hv, lv;
      bf16_split(o, hv, lv);
      outH[gp * 256 + c] = hv;
      outL[gp * 256 + c] = lv;
    }
  }
}

// ---------------------------------------------------------------------------
// Launch
// ---------------------------------------------------------------------------
extern "C" void kernel_launch(void* const* d_in, const int* in_sizes, int n_in,
                              void* d_out, int out_size, void* d_ws,
                              size_t ws_size, hipStream_t stream) {
  const float* xyz      = (const float*)d_in[0];
  const float* xy_embed = (const float*)d_in[1];
  const int*   nns      = (const int*)d_in[2];
  const float* ln1_g    = (const float*)d_in[3];
  const float* ln1_b    = (const float*)d_in[4];
  const float* w_qkv    = (const float*)d_in[5];
  const float* w_d1     = (const float*)d_in[6];
  const float* b_d1     = (const float*)d_in[7];
  const float* w_d2     = (const float*)d_in[8];
  const float* b_d2     = (const float*)d_in[9];
  const float* w_proj   = (const float*)d_in[10];
  const float* b_proj   = (const float*)d_in[11];
  const float* ln2_g    = (const float*)d_in[12];
  const float* ln2_b    = (const float*)d_in[13];
  const float* w_m1     = (const float*)d_in[14];
  const float* b_m1     = (const float*)d_in[15];
  const float* w_m2     = (const float*)d_in[16];
  const float* b_m2     = (const float*)d_in[17];
  float* out = (float*)d_out;

  char* ws = (char*)d_ws;
  const size_t MB = 1024 * 1024;
  ushort* qkv_bf = (ushort*)(ws);              // 48 MB  [BN][768] bf16
  ushort* midH   = (ushort*)(ws);              // 32 MB  (overlays qkv, dead by MLP)
  ushort* midL   = (ushort*)(ws + 32 * MB);    // 32 MB
  ushort* attnH  = (ushort*)(ws + 48 * MB);    // 16 MB
  ushort* attnL  = (ushort*)(ws + 64 * MB);    // 16 MB
  ushort* lnH    = (ushort*)(ws + 80 * MB);    // 16 MB
  ushort* lnL    = (ushort*)(ws + 96 * MB);    // 16 MB
  ushort* wbase  = (ushort*)(ws + 112 * MB);   // ~3.4 MB weights
  ushort* WqH  = wbase;             ushort* WqL  = WqH + 768 * 256;
  ushort* WpH  = WqL + 768 * 256;   ushort* WpL  = WpH + 256 * 256;
  ushort* Wm1H = WpL + 256 * 256;   ushort* Wm1L = Wm1H + 1024 * 256;
  ushort* Wm2H = Wm1L + 1024 * 256; ushort* Wm2L = Wm2H + 256 * 1024;
  ushort* W2H  = Wm2L + 256 * 1024; ushort* W2L  = W2H + 256 * 256;

  // 0. weight transpose + split (k-major hi/lo bf16)
  wsplit_kernel<<<dim3(768 / 32, 256 / 32), 256, 0, stream>>>(w_qkv, WqH, WqL, 256, 768);
  wsplit_kernel<<<dim3(256 / 32, 256 / 32), 256, 0, stream>>>(w_proj, WpH, WpL, 256, 256);
  wsplit_kernel<<<dim3(1024 / 32, 256 / 32), 256, 0, stream>>>(w_m1, Wm1H, Wm1L, 256, 1024);
  wsplit_kernel<<<dim3(256 / 32, 1024 / 32), 256, 0, stream>>>(w_m2, Wm2H, Wm2L, 1024, 256);
  wsplit_kernel<<<dim3(256 / 32, 256 / 32), 256, 0, stream>>>(w_d2, W2H, W2L, 256, 256);

  // 1. LN1 fused stats+apply -> pre-split A
  ln_apply_kernel<<<BN / 4, 256, 0, stream>>>(xy_embed, ln1_g, ln1_b, lnH, lnL);

  // 2. qkv = LN1(x) @ w_qkv -> bf16 table
  gemm_bf3<0><<<dim3(768 / 128, BN / 128), 256, 0, stream>>>(
      lnH, lnL, WqH, WqL, nullptr, nullptr, qkv_bf, nullptr, nullptr, BN, 768, 256);

  // 3. fused neighborhood attention (MFMA pe phase) -> pre-split attnout
  attn_kernel<<<BN / 8, 256, 0, stream>>>(qkv_bf, nns, xyz, w_d1, b_d1, W2H,
                                          b_d2, attnH, attnL);

  // 4. x = xy_embed + attnout @ w_proj + b_proj -> d_out (fp32)
  gemm_bf3<2><<<dim3(256 / 128, BN / 128), 256, 0, stream>>>(
      attnH, attnL, WpH, WpL, b_proj, out, nullptr, nullptr, xy_embed, BN, 256, 256);

  // 5. LN2 fused stats+apply
  ln_apply_kernel<<<BN / 4, 256, 0, stream>>>(out, ln2_g, ln2_b, lnH, lnL);

  // 6/7. MLP, chunked (mid overlays qkv region, dead by now)
  const int CHUNK = 16384;
  for (int ch = 0; ch < BN / CHUNK; ch++) {
    float* xrow = out + (size_t)ch * CHUNK * 256;
    gemm_bf3<3><<<dim3(1024 / 128, CHUNK / 128), 256, 0, stream>>>(
        lnH + (size_t)ch * CHUNK * 256, lnL + (size_t)ch * CHUNK * 256,
        Wm1H, Wm1L, b_m1, nullptr, midH, midL, nullptr, CHUNK, 1024, 256);
    gemm_bf3<2><<<dim3(256 / 128, CHUNK / 128), 256, 0, stream>>>(
        midH, midL, Wm2H, Wm2L, b_m2, xrow, nullptr, nullptr, xrow, CHUNK, 256, 1024);
  }
}

// Round 9
// 606.870 us; speedup vs baseline: 1.0070x; 1.0070x over previous
//
#include <hip/hip_runtime.h>
#include <hip/hip_bf16.h>
#include <math.h>

// Problem constants
#define NPTS 8192
#define BDIM 4
#define BN   32768   // BDIM*NPTS
#define CDIM 256
#define KNN  16
#define NNCOL 32

typedef __attribute__((ext_vector_type(8))) short short8_t;
typedef __attribute__((ext_vector_type(4))) float f32x4;

// ---------------------------------------------------------------------------
// bf16 helpers
// ---------------------------------------------------------------------------
__device__ __forceinline__ ushort bf16_rne(float f) {
  unsigned int u = __float_as_uint(f);
  u += 0x7fffu + ((u >> 16) & 1u);
  return (ushort)(u >> 16);
}
__device__ __forceinline__ void bf16_split(float f, ushort& h, ushort& l) {
  unsigned int u = __float_as_uint(f);
  h = (ushort)(u >> 16);
  float fh = __uint_as_float(u & 0xffff0000u);
  l = (ushort)(__float_as_uint(f - fh) >> 16);
}
__device__ __forceinline__ float bf16_tof(ushort h) {
  return __uint_as_float(((unsigned int)h) << 16);
}
__device__ __forceinline__ float gelu_exact(float z) {
  return 0.5f * z * (1.0f + erff(z * 0.70710678118654752f));
}

// ---------------------------------------------------------------------------
// Weight prep: transpose fp32 [R][Cc] -> hi/lo bf16 [Cc][R] (k-major for GEMM B)
// ---------------------------------------------------------------------------
__global__ __launch_bounds__(256) void wsplit_kernel(
    const float* __restrict__ in, ushort* __restrict__ oh,
    ushort* __restrict__ ol, int R, int Cc) {
  __shared__ float tile[32][33];
  const int tx = threadIdx.x & 31, ty = threadIdx.x >> 5;
  const int r0 = blockIdx.y * 32, c0 = blockIdx.x * 32;
  #pragma unroll
  for (int i = 0; i < 4; i++)
    tile[ty + 8 * i][tx] = in[(size_t)(r0 + ty + 8 * i) * Cc + c0 + tx];
  __syncthreads();
  #pragma unroll
  for (int i = 0; i < 4; i++) {
    const int cc = ty + 8 * i;
    ushort h, l;
    bf16_split(tile[tx][cc], h, l);
    oh[(size_t)(c0 + cc) * R + r0 + tx] = h;
    ol[(size_t)(c0 + cc) * R + r0 + tx] = l;
  }
}

// ---------------------------------------------------------------------------
// Fused LN stats + apply: x fp32 [rows][256] -> pre-split hi/lo bf16 of LN(x).
// ---------------------------------------------------------------------------
__global__ __launch_bounds__(256) void ln_apply_kernel(
    const float* __restrict__ x, const float* __restrict__ g,
    const float* __restrict__ b, ushort* __restrict__ oh,
    ushort* __restrict__ ol) {
  const int row = blockIdx.x * 4 + (threadIdx.x >> 6);
  const int l = threadIdx.x & 63;
  const float4 v = *(const float4*)(x + (size_t)row * CDIM + l * 4);
  float s  = v.x + v.y + v.z + v.w;
  float sq = v.x * v.x + v.y * v.y + v.z * v.z + v.w * v.w;
  #pragma unroll
  for (int off = 1; off < 64; off <<= 1) {
    s  += __shfl_xor(s, off);
    sq += __shfl_xor(sq, off);
  }
  const float m = s * (1.0f / 256.0f);
  const float r = rsqrtf(sq * (1.0f / 256.0f) - m * m + 1e-5f);
  const float4 gv = *(const float4*)(g + l * 4);
  const float4 bv = *(const float4*)(b + l * 4);
  const float y0 = (v.x - m) * r * gv.x + bv.x;
  const float y1 = (v.y - m) * r * gv.y + bv.y;
  const float y2 = (v.z - m) * r * gv.z + bv.z;
  const float y3 = (v.w - m) * r * gv.w + bv.w;
  ushort4 hv, lv;
  bf16_split(y0, hv.x, lv.x); bf16_split(y1, hv.y, lv.y);
  bf16_split(y2, hv.z, lv.z); bf16_split(y3, hv.w, lv.w);
  *(ushort4*)(oh + (size_t)row * CDIM + l * 4) = hv;
  *(ushort4*)(ol + (size_t)row * CDIM + l * 4) = lv;
}

// ---------------------------------------------------------------------------
// MFMA bf16x3 GEMM, pre-split operands (verified round 3/6 structure).
// ---------------------------------------------------------------------------
template <int EPI>
__global__ __launch_bounds__(256) void gemm_bf3(
    const ushort* __restrict__ AH, const ushort* __restrict__ AL,
    const ushort* __restrict__ BH, const ushort* __restrict__ BL,
    const float* __restrict__ bias, float* __restrict__ Cf,
    ushort* __restrict__ CH, ushort* __restrict__ CL,
    const float* __restrict__ res, int M, int Nn, int Kk) {
  __shared__ __align__(16) ushort AsH[128 * 32];
  __shared__ __align__(16) ushort AsL[128 * 32];
  __shared__ __align__(16) ushort BsH[128 * 32];
  __shared__ __align__(16) ushort BsL[128 * 32];

  const int t = threadIdx.x;
  const int w = t >> 6;
  const int l = t & 63;
  const int la = l & 15;
  const int lb = l >> 4;
  const int wr = w >> 1;
  const int wc = w & 1;
  const int m0 = blockIdx.y * 128;
  const int n0 = blockIdx.x * 128;

  f32x4 acc[4][4];
  #pragma unroll
  for (int i = 0; i < 4; i++)
    #pragma unroll
    for (int j = 0; j < 4; j++) acc[i][j] = (f32x4){0.f, 0.f, 0.f, 0.f};

  for (int k0 = 0; k0 < Kk; k0 += 32) {
    #pragma unroll
    for (int gi = 0; gi < 2; gi++) {
      const int g = t + gi * 256;
      const int row = g >> 2;
      const int kg = (g & 3) * 8;
      const int lds_off = row * 32 + (kg ^ ((row & 3) << 3));
      const size_t ga = (size_t)(m0 + row) * Kk + k0 + kg;
      const size_t gb = (size_t)(n0 + row) * Kk + k0 + kg;
      *(short8_t*)&AsH[lds_off] = *(const short8_t*)(AH + ga);
      *(short8_t*)&AsL[lds_off] = *(const short8_t*)(AL + ga);
      *(short8_t*)&BsH[lds_off] = *(const short8_t*)(BH + gb);
      *(short8_t*)&BsL[lds_off] = *(const short8_t*)(BL + gb);
    }
    __syncthreads();

    short8_t aH[4], aL[4], bH[4], bL[4];
    #pragma unroll
    for (int i = 0; i < 4; i++) {
      const int row = wr * 64 + i * 16 + la;
      const int off = row * 32 + ((lb * 8) ^ ((row & 3) << 3));
      aH[i] = *(const short8_t*)&AsH[off];
      aL[i] = *(const short8_t*)&AsL[off];
    }
    #pragma unroll
    for (int j = 0; j < 4; j++) {
      const int row = wc * 64 + j * 16 + la;
      const int off = row * 32 + ((lb * 8) ^ ((row & 3) << 3));
      bH[j] = *(const short8_t*)&BsH[off];
      bL[j] = *(const short8_t*)&BsL[off];
    }
    #pragma unroll
    for (int i = 0; i < 4; i++)
      #pragma unroll
      for (int j = 0; j < 4; j++) {
        acc[i][j] = __builtin_amdgcn_mfma_f32_16x16x32_bf16(aH[i], bH[j], acc[i][j], 0, 0, 0);
        acc[i][j] = __builtin_amdgcn_mfma_f32_16x16x32_bf16(aH[i], bL[j], acc[i][j], 0, 0, 0);
        acc[i][j] = __builtin_amdgcn_mfma_f32_16x16x32_bf16(aL[i], bH[j], acc[i][j], 0, 0, 0);
      }
    __syncthreads();
  }

  const int colBase = n0 + wc * 64 + la;
  float biasv[4] = {0.f, 0.f, 0.f, 0.f};
  if (EPI >= 2) {
    #pragma unroll
    for (int j = 0; j < 4; j++) biasv[j] = bias[colBase + j * 16];
  }
  #pragma unroll
  for (int i = 0; i < 4; i++) {
    #pragma unroll
    for (int r = 0; r < 4; r++) {
      const int row = m0 + wr * 64 + i * 16 + lb * 4 + r;
      #pragma unroll
      for (int j = 0; j < 4; j++) {
        const int col = colBase + j * 16;
        float o = acc[i][j][r] + biasv[j];
        if (EPI == 0) {
          CH[(size_t)row * Nn + col] = bf16_rne(o);
        } else if (EPI == 2) {
          o += res[(size_t)row * Nn + col];
          Cf[(size_t)row * Nn + col] = o;
        } else {  // EPI == 3
          o = gelu_exact(o);
          ushort h, lo2;
          bf16_split(o, h, lo2);
          CH[(size_t)row * Nn + col] = h;
          CL[(size_t)row * Nn + col] = lo2;
        }
      }
    }
  }
}

// ---------------------------------------------------------------------------
// Fused attention v4: 1 point per wave, 4 points per block (TLP-oriented).
//  Phase 1: shuffle-free scores (lane l = head l>>4, neighbor l&15), softmax
//  in-wave (no barrier), V + pe-basis accumulation; s -> bf16 swizzled LDS.
//  Phase 2 (after single barrier): pe = s @ w_d2 via MFMA over the block's
//  16 s-rows; fused add of ov(+b_d2); pre-split hi/lo bf16 output.
// ---------------------------------------------------------------------------
__global__ __launch_bounds__(256, 4) void attn_kernel(
    const ushort* __restrict__ qkv, const int* __restrict__ nns,
    const float* __restrict__ xyz, const float* __restrict__ w_d1,
    const float* __restrict__ b_d1, const ushort* __restrict__ W2H,
    const float* __restrict__ b_d2, ushort* __restrict__ outH,
    ushort* __restrict__ outL) {
  __shared__ __align__(16) ushort s_lds[16 * 256];  // row = p*4+h, swizzled
  __shared__ __align__(16) float ov_lds[4][256];
  __shared__ float a_lds[4][64];

  const int t = threadIdx.x;
  const int w = t >> 6;     // wave id == point within block
  const int l = t & 63;
  const int h = l >> 4;     // head for this lane (score + c0 quad)
  const int j16 = l & 15;   // score neighbor for this lane
  const int c0 = l * 4;
  const int blk = blockIdx.x;

  const float4 w10 = *(const float4*)(w_d1 + c0);
  const float4 w11 = *(const float4*)(w_d1 + 256 + c0);
  const float4 b1v = *(const float4*)(b_d1 + c0);
  const float4 b2v = *(const float4*)(b_d2 + c0);

  const int p  = w;
  const int gp = blk * 4 + p;
  const int b  = gp >> 13;

  const float2 xy0 = *(const float2*)(xyz + gp * 2);

  int rowj[KNN];
  #pragma unroll
  for (int j = 0; j < KNN; j++) rowj[j] = (b << 13) + nns[gp * NNCOL + j];

  // ---- scores: lane l computes the full 64-ch dot for (head h, neighbor j16)
  const size_t qbase = (size_t)gp * 768 + (h << 6);
  const size_t kbase = (size_t)rowj[j16] * 768 + 256 + (h << 6);
  float d = 0.f;
  #pragma unroll
  for (int u = 0; u < 8; u++) {
    const short8_t qv = *(const short8_t*)(qkv + qbase + u * 8);
    const short8_t kv = *(const short8_t*)(qkv + kbase + u * 8);
    #pragma unroll
    for (int e = 0; e < 8; e++)
      d += bf16_tof((ushort)qv[e]) * bf16_tof((ushort)kv[e]);
  }
  const float myscore = d * 0.125f;  // 1/sqrt(64)

  // softmax across the 16-lane group (axis j)
  float mx = myscore;
  mx = fmaxf(mx, __shfl_xor(mx, 1)); mx = fmaxf(mx, __shfl_xor(mx, 2));
  mx = fmaxf(mx, __shfl_xor(mx, 4)); mx = fmaxf(mx, __shfl_xor(mx, 8));
  const float e = __expf(myscore - mx);
  float sum = e;
  sum += __shfl_xor(sum, 1); sum += __shfl_xor(sum, 2);
  sum += __shfl_xor(sum, 4); sum += __shfl_xor(sum, 8);
  a_lds[p][l] = e / sum;  // l = h*16 + j; same-wave producer/consumer, no barrier

  // ---- V + pe-basis accumulation over the lane's channel quad c0
  float sacc[4][4] = {};
  float4 ov = {0.f, 0.f, 0.f, 0.f};
  #pragma unroll
  for (int j = 0; j < KNN; j++) {
    const int r = rowj[j];
    const ushort4 vu = *(const ushort4*)(qkv + (size_t)r * 768 + 512 + c0);
    const float v0 = bf16_tof(vu.x), v1 = bf16_tof(vu.y);
    const float v2 = bf16_tof(vu.z), v3 = bf16_tof(vu.w);
    const float2 xyj = *(const float2*)(xyz + r * 2);
    const float rx = xy0.x - xyj.x;
    const float ry = xy0.y - xyj.y;
    const float u0 = fmaxf(rx * w10.x + ry * w11.x + b1v.x, 0.f);
    const float u1 = fmaxf(rx * w10.y + ry * w11.y + b1v.y, 0.f);
    const float u2 = fmaxf(rx * w10.z + ry * w11.z + b1v.z, 0.f);
    const float u3 = fmaxf(rx * w10.w + ry * w11.w + b1v.w, 0.f);
    const float a0 = a_lds[p][0 * 16 + j];
    const float a1 = a_lds[p][1 * 16 + j];
    const float a2 = a_lds[p][2 * 16 + j];
    const float a3 = a_lds[p][3 * 16 + j];
    sacc[0][0] += a0 * u0; sacc[0][1] += a0 * u1; sacc[0][2] += a0 * u2; sacc[0][3] += a0 * u3;
    sacc[1][0] += a1 * u0; sacc[1][1] += a1 * u1; sacc[1][2] += a1 * u2; sacc[1][3] += a1 * u3;
    sacc[2][0] += a2 * u0; sacc[2][1] += a2 * u1; sacc[2][2] += a2 * u2; sacc[2][3] += a2 * u3;
    sacc[3][0] += a3 * u0; sacc[3][1] += a3 * u1; sacc[3][2] += a3 * u2; sacc[3][3] += a3 * u3;
    const float aown = a_lds[p][(h << 4) + j];
    ov.x += aown * v0; ov.y += aown * v1;
    ov.z += aown * v2; ov.w += aown * v3;
  }
  // s -> bf16 swizzled LDS (row = p*4+h, k = c')
  #pragma unroll
  for (int hh = 0; hh < 4; hh++) {
    const int row = p * 4 + hh;
    ushort4 sv;
    sv.x = bf16_rne(sacc[hh][0]); sv.y = bf16_rne(sacc[hh][1]);
    sv.z = bf16_rne(sacc[hh][2]); sv.w = bf16_rne(sacc[hh][3]);
    *(ushort4*)&s_lds[row * 256 + (c0 ^ (row << 3))] = sv;
  }
  float4 ovw;
  ovw.x = ov.x + b2v.x; ovw.y = ov.y + b2v.y;
  ovw.z = ov.z + b2v.z; ovw.w = ov.w + b2v.w;
  *(float4*)&ov_lds[p][c0] = ovw;
  __syncthreads();

  // ---- Phase 2: pe = s @ w_d2 via MFMA. Wave w covers cols w*64..w*64+63
  // (= head w) for all 4 points. A = s_lds [16 rows][256 k]; B = W2H [n][k].
  const int la = l & 15;
  const int lb = l >> 4;
  f32x4 acc2[4];
  #pragma unroll
  for (int nf = 0; nf < 4; nf++) acc2[nf] = (f32x4){0.f, 0.f, 0.f, 0.f};

  #pragma unroll
  for (int ks = 0; ks < 8; ks++) {
    const int k8 = lb * 8 + ks * 32;
    const int arow = la;
    const short8_t av = *(const short8_t*)&s_lds[arow * 256 + (k8 ^ (arow << 3))];
    #pragma unroll
    for (int nf = 0; nf < 4; nf++) {
      const int n = (w << 6) + nf * 16 + la;
      const short8_t bv = *(const short8_t*)(W2H + (size_t)n * 256 + k8);
      acc2[nf] = __builtin_amdgcn_mfma_f32_16x16x32_bf16(av, bv, acc2[nf], 0, 0, 0);
    }
  }

  // Epilogue: useful lane data = acc2[nf][r=w] -> point p2 = lb,
  // col c = w*64 + nf*16 + la. Add ov(+b_d2), split, store.
  const int p2 = lb;
  const size_t gp2 = (size_t)(blk * 4 + p2);
  #pragma unroll
  for (int nf = 0; nf < 4; nf++) {
    const int c = (w << 6) + nf * 16 + la;
    float pe;
    if (w == 0)      pe = acc2[nf][0];
    else if (w == 1) pe = acc2[nf][1];
    else if (w == 2) pe = acc2[nf][2];
    else             pe = acc2[nf][3];
    const float o = pe + ov_lds[p2][c];
    ushort hv, lv;
    bf16_split(o, hv, lv);
    outH[gp2 * 256 + c] = hv;
    outL[gp2 * 256 + c] = lv;
  }
}

// ---------------------------------------------------------------------------
// Launch
// ---------------------------------------------------------------------------
extern "C" void kernel_launch(void* const* d_in, const int* in_sizes, int n_in,
                              void* d_out, int out_size, void* d_ws,
                              size_t ws_size, hipStream_t stream) {
  const float* xyz      = (const float*)d_in[0];
  const float* xy_embed = (const float*)d_in[1];
  const int*   nns      = (const int*)d_in[2];
  const float* ln1_g    = (const float*)d_in[3];
  const float* ln1_b    = (const float*)d_in[4];
  const float* w_qkv    = (const float*)d_in[5];
  const float* w_d1     = (const float*)d_in[6];
  const float* b_d1     = (const float*)d_in[7];
  const float* w_d2     = (const float*)d_in[8];
  const float* b_d2     = (const float*)d_in[9];
  const float* w_proj   = (const float*)d_in[10];
  const float* b_proj   = (const float*)d_in[11];
  const float* ln2_g    = (const float*)d_in[12];
  const float* ln2_b    = (const float*)d_in[13];
  const float* w_m1     = (const float*)d_in[14];
  const float* b_m1     = (const float*)d_in[15];
  const float* w_m2     = (const float*)d_in[16];
  const float* b_m2     = (const float*)d_in[17];
  float* out = (float*)d_out;

  char* ws = (char*)d_ws;
  const size_t MB = 1024 * 1024;
  ushort* qkv_bf = (ushort*)(ws);              // 48 MB  [BN][768] bf16
  ushort* midH   = (ushort*)(ws);              // 32 MB  (overlays qkv, dead by MLP)
  ushort* midL   = (ushort*)(ws + 32 * MB);    // 32 MB
  ushort* attnH  = (ushort*)(ws + 48 * MB);    // 16 MB
  ushort* attnL  = (ushort*)(ws + 64 * MB);    // 16 MB
  ushort* lnH    = (ushort*)(ws + 80 * MB);    // 16 MB
  ushort* lnL    = (ushort*)(ws + 96 * MB);    // 16 MB
  ushort* wbase  = (ushort*)(ws + 112 * MB);   // ~3.4 MB weights
  ushort* WqH  = wbase;             ushort* WqL  = WqH + 768 * 256;
  ushort* WpH  = WqL + 768 * 256;   ushort* WpL  = WpH + 256 * 256;
  ushort* Wm1H = WpL + 256 * 256;   ushort* Wm1L = Wm1H + 1024 * 256;
  ushort* Wm2H = Wm1L + 1024 * 256; ushort* Wm2L = Wm2H + 256 * 1024;
  ushort* W2H  = Wm2L + 256 * 1024; ushort* W2L  = W2H + 256 * 256;

  // 0. weight transpose + split (k-major hi/lo bf16)
  wsplit_kernel<<<dim3(768 / 32, 256 / 32), 256, 0, stream>>>(w_qkv, WqH, WqL, 256, 768);
  wsplit_kernel<<<dim3(256 / 32, 256 / 32), 256, 0, stream>>>(w_proj, WpH, WpL, 256, 256);
  wsplit_kernel<<<dim3(1024 / 32, 256 / 32), 256, 0, stream>>>(w_m1, Wm1H, Wm1L, 256, 1024);
  wsplit_kernel<<<dim3(256 / 32, 1024 / 32), 256, 0, stream>>>(w_m2, Wm2H, Wm2L, 1024, 256);
  wsplit_kernel<<<dim3(256 / 32, 256 / 32), 256, 0, stream>>>(w_d2, W2H, W2L, 256, 256);

  // 1. LN1 fused stats+apply -> pre-split A
  ln_apply_kernel<<<BN / 4, 256, 0, stream>>>(xy_embed, ln1_g, ln1_b, lnH, lnL);

  // 2. qkv = LN1(x) @ w_qkv -> bf16 table
  gemm_bf3<0><<<dim3(768 / 128, BN / 128), 256, 0, stream>>>(
      lnH, lnL, WqH, WqL, nullptr, nullptr, qkv_bf, nullptr, nullptr, BN, 768, 256);

  // 3. fused neighborhood attention (1 point/wave) -> pre-split attnout
  attn_kernel<<<BN / 4, 256, 0, stream>>>(qkv_bf, nns, xyz, w_d1, b_d1, W2H,
                                          b_d2, attnH, attnL);

  // 4. x = xy_embed + attnout @ w_proj + b_proj -> d_out (fp32)
  gemm_bf3<2><<<dim3(256 / 128, BN / 128), 256, 0, stream>>>(
      attnH, attnL, WpH, WpL, b_proj, out, nullptr, nullptr, xy_embed, BN, 256, 256);

  // 5. LN2 fused stats+apply
  ln_apply_kernel<<<BN / 4, 256, 0, stream>>>(out, ln2_g, ln2_b, lnH, lnL);

  // 6/7. MLP, chunked (mid overlays qkv region, dead by now)
  const int CHUNK = 16384;
  for (int ch = 0; ch < BN / CHUNK; ch++) {
    float* xrow = out + (size_t)ch * CHUNK * 256;
    gemm_bf3<3><<<dim3(1024 / 128, CHUNK / 128), 256, 0, stream>>>(
        lnH + (size_t)ch * CHUNK * 256, lnL + (size_t)ch * CHUNK * 256,
        Wm1H, Wm1L, b_m1, nullptr, midH, midL, nullptr, CHUNK, 1024, 256);
    gemm_bf3<2><<<dim3(256 / 128, CHUNK / 128), 256, 0, stream>>>(
        midH, midL, Wm2H, Wm2L, b_m2, xrow, nullptr, nullptr, xrow, CHUNK, 256, 1024);
  }
}